// Round 3
// baseline (742.904 us; speedup 1.0000x reference)
//
#include <hip/hip_runtime.h>
#include <stdint.h>

#define DIMS 256
#define NT 4096
#define NROWS 65536
#define CHUNK 8

// ---- numpy pairwise_sum(128) emulation: 8 accumulators + fixed combine tree ----
// ---- kernel 0a: sx[n] = np.sum(flat*flat, axis=1) bit-exact (pairwise 256 = P128 + P128) ----
__global__ void vq_sx(const float* __restrict__ x, float* __restrict__ sx){
  const int n = blockIdx.x * 64 + threadIdx.x;
  const int b = n >> 12, t = n & 4095;
  const float* xp = x + (size_t)b * DIMS * NT + t;
  float half[2];
  #pragma unroll
  for (int h = 0; h < 2; ++h){
    float r[8];
    #pragma unroll
    for (int j = 0; j < 8; ++j){
      float v = xp[(size_t)(h*128 + j) * NT];
      r[j] = __fmul_rn(v, v);
    }
    for (int i = 8; i < 128; i += 8){
      #pragma unroll
      for (int j = 0; j < 8; ++j){
        float v = xp[(size_t)(h*128 + i + j) * NT];
        r[j] = __fadd_rn(r[j], __fmul_rn(v, v));
      }
    }
    half[h] = __fadd_rn(__fadd_rn(__fadd_rn(r[0], r[1]), __fadd_rn(r[2], r[3])),
                        __fadd_rn(__fadd_rn(r[4], r[5]), __fadd_rn(r[6], r[7])));
  }
  sx[n] = __fadd_rn(half[0], half[1]);
}

// ---- kernel 0b: se[k] = np.sum(cb*cb, axis=1) bit-exact ----
__global__ void vq_se(const float* __restrict__ cb, float* __restrict__ se){
  const int k = blockIdx.x * 64 + threadIdx.x;
  const float* ep = cb + (size_t)k * DIMS;
  float half[2];
  #pragma unroll
  for (int h = 0; h < 2; ++h){
    float r[8];
    #pragma unroll
    for (int j = 0; j < 8; ++j){
      float v = ep[h*128 + j];
      r[j] = __fmul_rn(v, v);
    }
    for (int i = 8; i < 128; i += 8){
      #pragma unroll
      for (int j = 0; j < 8; ++j){
        float v = ep[h*128 + i + j];
        r[j] = __fadd_rn(r[j], __fmul_rn(v, v));
      }
    }
    half[h] = __fadd_rn(__fadd_rn(__fadd_rn(r[0], r[1]), __fadd_rn(r[2], r[3])),
                        __fadd_rn(__fadd_rn(r[4], r[5]), __fadd_rn(r[6], r[7])));
  }
  se[k] = __fadd_rn(half[0], half[1]);
}

// ---- kernel 1: fp32-emulated distances + argmin ----
// block = 32 rows (4 waves x 8 rows); lane covers 16 codes: k = j*256 + lane*4 + u.
// dot chain: s = fmaf(x_c, e_c, s) for c = 0..255 ascending (sgemm emulation).
__global__ __launch_bounds__(256) void vq_emu(
    const float* __restrict__ x, const float* __restrict__ cb,
    const float* __restrict__ sx, const float* __restrict__ se,
    int* __restrict__ idx, float* __restrict__ out2)
{
  __shared__ float eT[CHUNK][1024];   // 32 KiB, transposed codebook chunk
  __shared__ float xs[DIMS][32];      // 32 KiB, x rows (c-major for conflict-free writes)

  const int tid  = threadIdx.x;
  const int lane = tid & 63;
  const int wid  = tid >> 6;
  const int n0   = blockIdx.x * 32;
  const int b    = n0 >> 12;
  const int t0   = n0 & 4095;
  const int r0   = wid * 8;

  // stage x rows: id -> (c = id>>5, r = id&31), coalesced on r
  #pragma unroll
  for (int rep = 0; rep < 32; ++rep){
    int id = rep * 256 + tid;
    int c = id >> 5, r = id & 31;
    xs[c][r] = x[((size_t)(b * DIMS + c)) * NT + t0 + r];
  }

  float s[8][4][4];
  #pragma unroll
  for (int rr = 0; rr < 8; ++rr)
    #pragma unroll
    for (int j = 0; j < 4; ++j)
      #pragma unroll
      for (int u = 0; u < 4; ++u) s[rr][j][u] = 0.f;

  for (int c0 = 0; c0 < DIMS; c0 += CHUNK){
    __syncthreads();   // also covers xs staging on first iteration
    // stage eT[cc][k] via float4 reads: id2 -> (k = id2>>1, q = id2&1)
    #pragma unroll
    for (int rep = 0; rep < 8; ++rep){
      int id2 = rep * 256 + tid;
      int k = id2 >> 1, q = id2 & 1;
      float4 v = *(const float4*)&cb[(size_t)k * DIMS + c0 + q * 4];
      eT[q*4 + 0][k] = v.x; eT[q*4 + 1][k] = v.y;
      eT[q*4 + 2][k] = v.z; eT[q*4 + 3][k] = v.w;
    }
    __syncthreads();

    #pragma unroll
    for (int cc = 0; cc < CHUNK; ++cc){
      float4 ev0 = *(const float4*)&eT[cc][lane * 4];
      float4 ev1 = *(const float4*)&eT[cc][lane * 4 + 256];
      float4 ev2 = *(const float4*)&eT[cc][lane * 4 + 512];
      float4 ev3 = *(const float4*)&eT[cc][lane * 4 + 768];
      #pragma unroll
      for (int rr = 0; rr < 8; ++rr){
        float xv = xs[c0 + cc][r0 + rr];
        s[rr][0][0] = fmaf(xv, ev0.x, s[rr][0][0]);
        s[rr][0][1] = fmaf(xv, ev0.y, s[rr][0][1]);
        s[rr][0][2] = fmaf(xv, ev0.z, s[rr][0][2]);
        s[rr][0][3] = fmaf(xv, ev0.w, s[rr][0][3]);
        s[rr][1][0] = fmaf(xv, ev1.x, s[rr][1][0]);
        s[rr][1][1] = fmaf(xv, ev1.y, s[rr][1][1]);
        s[rr][1][2] = fmaf(xv, ev1.z, s[rr][1][2]);
        s[rr][1][3] = fmaf(xv, ev1.w, s[rr][1][3]);
        s[rr][2][0] = fmaf(xv, ev2.x, s[rr][2][0]);
        s[rr][2][1] = fmaf(xv, ev2.y, s[rr][2][1]);
        s[rr][2][2] = fmaf(xv, ev2.z, s[rr][2][2]);
        s[rr][2][3] = fmaf(xv, ev2.w, s[rr][2][3]);
        s[rr][3][0] = fmaf(xv, ev3.x, s[rr][3][0]);
        s[rr][3][1] = fmaf(xv, ev3.y, s[rr][3][1]);
        s[rr][3][2] = fmaf(xv, ev3.z, s[rr][3][2]);
        s[rr][3][3] = fmaf(xv, ev3.w, s[rr][3][3]);
      }
    }
  }

  // epilogue: d_k = fl32( fl32(sx + se_k) - fl32(2*m_k) ), lex argmin (first-occurrence)
  float sek[4][4];
  #pragma unroll
  for (int j = 0; j < 4; ++j)
    #pragma unroll
    for (int u = 0; u < 4; ++u) sek[j][u] = se[j * 256 + lane * 4 + u];

  #pragma unroll
  for (int rr = 0; rr < 8; ++rr){
    const int n = n0 + r0 + rr;
    const float sxv = sx[n];
    float bv = 3.4e38f; int bi = 0x7fffffff;
    #pragma unroll
    for (int j = 0; j < 4; ++j){
      #pragma unroll
      for (int u = 0; u < 4; ++u){
        float d = __fsub_rn(__fadd_rn(sxv, sek[j][u]),
                            __fadd_rn(s[rr][j][u], s[rr][j][u]));
        int k = j * 256 + lane * 4 + u;
        if (d < bv || (d == bv && k < bi)) { bv = d; bi = k; }
      }
    }
    #pragma unroll
    for (int m = 1; m < 64; m <<= 1){
      float ov = __shfl_xor(bv, m);
      int   oi = __shfl_xor(bi, m);
      if (ov < bv || (ov == bv && oi < bi)) { bv = ov; bi = oi; }
    }
    if (lane == 0){ idx[n] = bi; out2[n] = (float)bi; }
  }
}

// ---- kernel 2: gather quantized (== quantized_st), accumulate loss ----
__global__ __launch_bounds__(256) void vq_gather(
    const float* __restrict__ x, const float* __restrict__ cb,
    const int* __restrict__ idx, float* __restrict__ out0, double* __restrict__ acc)
{
  const int bc = blockIdx.x;          // b*256 + c
  const int bb = bc >> 8;
  const int c  = bc & 255;
  const float* xr = x + (size_t)bc * NT;
  float* orow = out0 + (size_t)bc * NT;
  const int* ir = idx + bb * NT;
  float s = 0.f;
  #pragma unroll
  for (int j = 0; j < 4; ++j){
    const int t = (threadIdx.x << 2) + (j << 10);
    float4 xv = *(const float4*)(xr + t);
    int4  iv  = *(const int4*)(ir + t);
    float4 q;
    q.x = cb[iv.x * DIMS + c];
    q.y = cb[iv.y * DIMS + c];
    q.z = cb[iv.z * DIMS + c];
    q.w = cb[iv.w * DIMS + c];
    float dx = q.x - xv.x, dy = q.y - xv.y, dz = q.z - xv.z, dw = q.w - xv.w;
    s += dx*dx + dy*dy + dz*dz + dw*dw;
    *(float4*)(orow + t) = q;
  }
  #pragma unroll
  for (int m = 1; m < 64; m <<= 1) s += __shfl_xor(s, m);
  __shared__ float wsum[4];
  if ((threadIdx.x & 63) == 0) wsum[threadIdx.x >> 6] = s;
  __syncthreads();
  if (threadIdx.x == 0){
    double tot = (double)wsum[0] + (double)wsum[1] + (double)wsum[2] + (double)wsum[3];
    atomicAdd(acc, tot);
  }
}

__global__ void vq_final(const double* __restrict__ acc, float* __restrict__ out1){
  *out1 = (float)(1.25 * (*acc) * (1.0 / 16777216.0));
}

extern "C" void kernel_launch(void* const* d_in, const int* in_sizes, int n_in,
                              void* d_out, int out_size, void* d_ws, size_t ws_size,
                              hipStream_t stream)
{
  const float* x  = (const float*)d_in[0];
  const float* cb = (const float*)d_in[1];
  float* out  = (float*)d_out;
  float* out0 = out;
  float* out1 = out + (size_t)16777216;   // vq_loss
  float* out2 = out + (size_t)16777217;   // indices as float [65536]

  char* ws = (char*)d_ws;
  double* acc = (double*)(ws + 0);
  float*  se  = (float*)(ws + 64);        // 4 KiB
  float*  sx  = (float*)(ws + 4160);      // 256 KiB
  int*    idx = (int*)(ws + 266304);      // 256 KiB

  hipMemsetAsync(d_ws, 0, 16, stream);    // zero loss accumulator
  vq_sx    <<<dim3(1024), dim3(64),  0, stream>>>(x, sx);
  vq_se    <<<dim3(16),   dim3(64),  0, stream>>>(cb, se);
  vq_emu   <<<dim3(2048), dim3(256), 0, stream>>>(x, cb, sx, se, idx, out2);
  vq_gather<<<dim3(4096), dim3(256), 0, stream>>>(x, cb, idx, out0, acc);
  vq_final <<<dim3(1),    dim3(1),   0, stream>>>(acc, out1);
}